// Round 5
// baseline (328.034 us; speedup 1.0000x reference)
//
#include <hip/hip_runtime.h>
#include <cmath>

// ---------------------------------------------------------------------------
// min_max_net: w' = weight with montn columns squared; y = x @ w'^T + bias;
// out[b] = (rand_u[b] < sigmoid(max_g min_{j in g} y[b, g*64+j])) ? 1 : 0
//
// R5: GEMM on mfma_f32_32x32x16_f16, block 128x128 / wave 64x64 (acc=64
// VGPR -> 4 blocks/CU via __launch_bounds__(256,4)); XCD n-slice swizzle
// (per-XCD W slice 2MB, L2-resident). Dispatches 7->5: mask folded into
// convert, ybuf-zero folded into finalize, recompute at (64,16) 33KB LDS.
// fp16 hi*hi GEMM (sigma ~3.6e-4), margin 4e-3, exact fp32 recompute of
// undecided rows (~16 expected, cap 96).
// ---------------------------------------------------------------------------

typedef _Float16 f16x8 __attribute__((ext_vector_type(8)));
typedef float f32x16 __attribute__((ext_vector_type(16)));

#define MARGIN_EPS 4e-3f
#define MAX_UNDEC 96

__device__ __forceinline__ void async_load16(const void* gptr, void* lptr) {
  __builtin_amdgcn_global_load_lds(
      (const __attribute__((address_space(1))) void*)gptr,
      (__attribute__((address_space(3))) void*)lptr, 16, 0, 0);
}

__device__ __forceinline__ float us2f(unsigned short u) {
  return (float)__builtin_bit_cast(_Float16, u);
}

// ---- kernel 1: in-place fp32 row -> [hi fp16 | lo fp16], 1 wave per row ----
// Mask built per-block in LDS (blocks >= 2048 handle weight rows).
// In-wave ordering: all 8 loads precede any store (aliasing keeps order).
__global__ void convert_split(float* __restrict__ x, float* __restrict__ wgt,
                              const int* __restrict__ montn,
                              int* __restrict__ count) {
  __shared__ unsigned msk[64];
  const int t = threadIdx.x, l = t & 63, w = t >> 6;
  const int r = blockIdx.x * 4 + w;
  const int use_mask = (r >= 8192) ? 1 : 0;   // block-uniform (4-row blocks)
  if (blockIdx.x == 0 && t == 0) *count = 0;
  if (use_mask) {
    if (t < 64) msk[t] = 0u;
    __syncthreads();
    for (int j = t; j < 512; j += 256) {
      const int c = montn[j];
      atomicOr(&msk[c >> 5], 1u << (c & 31));
    }
    __syncthreads();
  }
  float* rowp = use_mask ? (wgt + (size_t)(r - 8192) * 2048)
                         : (x + (size_t)r * 2048);
  float4 v[8];
#pragma unroll
  for (int j = 0; j < 8; ++j) v[j] = ((const float4*)rowp)[l + 64 * j];
  unsigned mw[8];
#pragma unroll
  for (int j = 0; j < 8; ++j)
    mw[j] = use_mask ? msk[(l >> 3) + 8 * j] : 0u;

  unsigned short* up = (unsigned short*)rowp;
#pragma unroll
  for (int j = 0; j < 8; ++j) {
    unsigned short hs[4], ls[4];
    const float* fv = (const float*)&v[j];
#pragma unroll
    for (int c = 0; c < 4; ++c) {
      float f = fv[c];
      if ((mw[j] >> (4 * (l & 7) + c)) & 1u) f = f * f;
      _Float16 h = (_Float16)f;          // RTNE
      float res = f - (float)h;          // exact in fp32
      _Float16 lo = (_Float16)res;
      hs[c] = __builtin_bit_cast(unsigned short, h);
      ls[c] = __builtin_bit_cast(unsigned short, lo);
    }
    uint2 H, L;
    H.x = (unsigned)hs[0] | ((unsigned)hs[1] << 16);
    H.y = (unsigned)hs[2] | ((unsigned)hs[3] << 16);
    L.x = (unsigned)ls[0] | ((unsigned)ls[1] << 16);
    L.y = (unsigned)ls[2] | ((unsigned)ls[3] << 16);
    *((uint2*)(up + 4 * l + 256 * j)) = H;           // hi plane [0,2048)
    *((uint2*)(up + 2048 + 4 * l + 256 * j)) = L;    // lo plane [2048,4096)
  }
}

// ---- kernel 2: hi*hi GEMM + fused bias/group-min ---------------------------
// Block 128x128, BK=64, 4 waves (2x2), wave 64x64 via 2x2 MFMA 32x32x16 f16.
// XOR-swizzled LDS chunks (verified zero conflicts R2-R4). XCD n-slicing:
// lin&7 picks XCD; each XCD owns 4 n-blocks (2MB W hi slice, L2-resident).
__global__ __launch_bounds__(256, 4) void gemm_minmax(
    const unsigned short* __restrict__ X, const unsigned short* __restrict__ W,
    const float* __restrict__ bias, float* __restrict__ gmins) {
  __shared__ unsigned short As[128 * 64];   // 16 KB
  __shared__ unsigned short Bs[128 * 64];   // 16 KB
  const int t = threadIdx.x;
  const int lane = t & 63;
  const int w = t >> 6;
  const int wm = w >> 1, wn = w & 1;
  // swizzle: grid 2048 = 64 m-blocks x 32 n-blocks; XCD (lin&7) gets n-slice.
  const int lin = blockIdx.x;
  const int sid = lin >> 3;
  const int m0 = (sid >> 2) * 128;
  const int n0 = ((lin & 7) * 4 + (sid & 3)) * 128;

  // staging: call c covers rows [c*32, c*32+32); lane row = c*32+w*8+(l>>3),
  // stored chunk l&7 holds global chunk (l&7)^(row&7)  (row&7 == (l>>3)&7).
  const int rowBase = w * 8 + (lane >> 3);
  const int gchunk = ((lane & 7) ^ ((lane >> 3) & 7)) * 8;  // ushort offset
  size_t sA[4], sB[4];
#pragma unroll
  for (int c = 0; c < 4; ++c) {
    sA[c] = (size_t)(m0 + c * 32 + rowBase) * 4096 + gchunk;
    sB[c] = (size_t)(n0 + c * 32 + rowBase) * 4096 + gchunk;
  }
  unsigned short* ldsA[4];
  unsigned short* ldsB[4];
#pragma unroll
  for (int c = 0; c < 4; ++c) {
    ldsA[c] = As + c * 2048 + w * 512;  // wave-uniform bases (ushort units)
    ldsB[c] = Bs + c * 2048 + w * 512;
  }

  // fragment geometry (32x32x16): lane holds A[m=l&31][k=(l>>5)*8+j].
  const int l31 = lane & 31, hi32 = lane >> 5;
  int arow[2], brow[2], swz[4];
#pragma unroll
  for (int i = 0; i < 2; ++i) {
    arow[i] = (wm * 64 + i * 32 + l31) * 64;   // row&7 == lane&7
    brow[i] = (wn * 64 + i * 32 + l31) * 64;
  }
#pragma unroll
  for (int s = 0; s < 4; ++s) swz[s] = ((2 * s + hi32) ^ (lane & 7)) * 8;

  f32x16 acc[2][2];
#pragma unroll
  for (int i = 0; i < 2; ++i)
#pragma unroll
    for (int j = 0; j < 2; ++j) acc[i][j] = (f32x16)(0.f);

#pragma unroll 1
  for (int it = 0; it < 32; ++it) {
    const int kin = it * 64;
    __syncthreads();  // previous iteration's LDS reads complete
#pragma unroll
    for (int c = 0; c < 4; ++c) {
      async_load16(X + sA[c] + kin, ldsA[c]);
      async_load16(W + sB[c] + kin, ldsB[c]);
    }
    __syncthreads();  // staging complete (drains vmcnt)

#pragma unroll
    for (int s = 0; s < 4; ++s) {   // 4 k-steps of K=16
      f16x8 a0 = *(const f16x8*)(As + arow[0] + swz[s]);
      f16x8 a1 = *(const f16x8*)(As + arow[1] + swz[s]);
      f16x8 b0 = *(const f16x8*)(Bs + brow[0] + swz[s]);
      f16x8 b1 = *(const f16x8*)(Bs + brow[1] + swz[s]);
      acc[0][0] = __builtin_amdgcn_mfma_f32_32x32x16_f16(a0, b0, acc[0][0], 0, 0, 0);
      acc[0][1] = __builtin_amdgcn_mfma_f32_32x32x16_f16(a0, b1, acc[0][1], 0, 0, 0);
      acc[1][0] = __builtin_amdgcn_mfma_f32_32x32x16_f16(a1, b0, acc[1][0], 0, 0, 0);
      acc[1][1] = __builtin_amdgcn_mfma_f32_32x32x16_f16(a1, b1, acc[1][1], 0, 0, 0);
    }
  }

  // epilogue: wave's 64 cols == one group. C/D: col=l31, row=(r&3)+8*(r>>2)+4*hi32.
  float bia[2];
#pragma unroll
  for (int nt = 0; nt < 2; ++nt) bia[nt] = bias[n0 + wn * 64 + nt * 32 + l31];
  const int grp = (n0 >> 6) + wn;
#pragma unroll
  for (int mt = 0; mt < 2; ++mt) {
#pragma unroll
    for (int r = 0; r < 16; ++r) {
      float v = fminf(acc[mt][0][r] + bia[0], acc[mt][1][r] + bia[1]);
      v = fminf(v, __shfl_xor(v, 1, 64));
      v = fminf(v, __shfl_xor(v, 2, 64));
      v = fminf(v, __shfl_xor(v, 4, 64));
      v = fminf(v, __shfl_xor(v, 8, 64));
      v = fminf(v, __shfl_xor(v, 16, 64));
      if (l31 == 0) {
        const int row = m0 + wm * 64 + mt * 32 + (r & 3) + 8 * (r >> 2) + 4 * hi32;
        gmins[(size_t)row * 64 + grp] = v;
      }
    }
  }
}

// ---- kernel 3: max over groups -> margin test (+ ybuf zeroing) -------------
__global__ void finalize_margin(const float* __restrict__ gmins,
                                const float* __restrict__ rand_u,
                                float* __restrict__ out,
                                int* __restrict__ count, int* __restrict__ undec,
                                float4* __restrict__ ybuf4) {
  if (blockIdx.x < 384)  // zero ybuf: 384*256 float4 = 96*4096 floats
    ybuf4[(size_t)blockIdx.x * 256 + threadIdx.x] = (float4){0.f, 0.f, 0.f, 0.f};
  const int wv = threadIdx.x >> 6, lane = threadIdx.x & 63;
  const int row = blockIdx.x * 4 + wv;
  float v = gmins[(size_t)row * 64 + lane];
  v = fmaxf(v, __shfl_xor(v, 1, 64));
  v = fmaxf(v, __shfl_xor(v, 2, 64));
  v = fmaxf(v, __shfl_xor(v, 4, 64));
  v = fmaxf(v, __shfl_xor(v, 8, 64));
  v = fmaxf(v, __shfl_xor(v, 16, 64));
  v = fmaxf(v, __shfl_xor(v, 32, 64));
  if (lane == 0) {
    const float u = rand_u[row];
    const float slo = 1.0f / (1.0f + expf(-(v - MARGIN_EPS)));
    const float shi = 1.0f / (1.0f + expf(-(v + MARGIN_EPS)));
    if (u < slo) {
      out[row] = 1.0f;
    } else if (u >= shi) {
      out[row] = 0.0f;
    } else {
      const int i = atomicAdd(count, 1);
      if (i < 8192) undec[i] = row;
    }
  }
}

// ---- kernel 4: exact fp32 recompute, W read ONCE ---------------------------
// grid (64 groups, 16 k-chunks of 128). Block stages its W chunk (64 cols x
// 128 k) reconstructed fp32 in LDS (stride 129, conflict-free reads), loops
// undecided slots, atomicAdd partial dot into ybuf[s][col].
__global__ __launch_bounds__(256) void recompute_rows(
    const unsigned short* __restrict__ X, const unsigned short* __restrict__ W,
    const int* __restrict__ count, const int* __restrict__ undec,
    float* __restrict__ ybuf) {
  __shared__ float wf[64 * 129];   // ~33 KB
  __shared__ float part[256];
  const int g = blockIdx.x, kc = blockIdx.y;
  const int t = threadIdx.x;
  int n = *count;
  if (n > MAX_UNDEC) n = MAX_UNDEC;
  if (n == 0) return;

  {  // stage: thread t -> col t>>2, k-segment t&3 (32 k each)
    const int cl = t >> 2, ks = t & 3;
    const unsigned short* wp =
        W + (size_t)(g * 64 + cl) * 4096 + kc * 128 + ks * 32;
    float* dst = wf + cl * 129 + ks * 32;
#pragma unroll
    for (int i = 0; i < 32; i += 8) {
      uint4 hv = *(const uint4*)(wp + i);
      uint4 lv = *(const uint4*)(wp + 2048 + i);
      const unsigned* hw = (const unsigned*)&hv;
      const unsigned* lw = (const unsigned*)&lv;
#pragma unroll
      for (int m = 0; m < 4; ++m) {
        dst[i + 2 * m] = us2f((unsigned short)(hw[m] & 0xFFFF)) +
                         us2f((unsigned short)(lw[m] & 0xFFFF));
        dst[i + 2 * m + 1] = us2f((unsigned short)(hw[m] >> 16)) +
                             us2f((unsigned short)(lw[m] >> 16));
      }
    }
  }
  __syncthreads();

  const int col = t & 63, kq = t >> 6;   // 32 k per quarter
  const float* wcol = wf + col * 129 + kq * 32;
  for (int s = 0; s < n; ++s) {
    const int row = undec[s];
    const unsigned short* xp = X + (size_t)row * 4096 + kc * 128 + kq * 32;
    float acc = 0.f;
#pragma unroll
    for (int i = 0; i < 32; i += 8) {
      uint4 hv = *(const uint4*)(xp + i);
      uint4 lv = *(const uint4*)(xp + 2048 + i);
      const unsigned* hw = (const unsigned*)&hv;
      const unsigned* lw = (const unsigned*)&lv;
#pragma unroll
      for (int m = 0; m < 4; ++m) {
        const float x0 = us2f((unsigned short)(hw[m] & 0xFFFF)) +
                         us2f((unsigned short)(lw[m] & 0xFFFF));
        const float x1 = us2f((unsigned short)(hw[m] >> 16)) +
                         us2f((unsigned short)(lw[m] >> 16));
        acc = fmaf(x0, wcol[i + 2 * m], acc);
        acc = fmaf(x1, wcol[i + 2 * m + 1], acc);
      }
    }
    part[t] = acc;
    __syncthreads();
    if (t < 64) {
      const float y = part[t] + part[t + 64] + part[t + 128] + part[t + 192];
      atomicAdd(ybuf + (size_t)s * 4096 + g * 64 + t, y);
    }
    __syncthreads();
  }
}

// ---- kernel 5: final decision for undecided rows ---------------------------
__global__ void decide(const float* __restrict__ ybuf,
                       const int* __restrict__ undec, const int* __restrict__ count,
                       const float* __restrict__ bias,
                       const float* __restrict__ rand_u, float* __restrict__ out) {
  __shared__ float gm[64];
  int n = *count;
  if (n > MAX_UNDEC) n = MAX_UNDEC;
  const int s = blockIdx.x;
  if (s >= n) return;
  const int t = threadIdx.x;
  const int g = t >> 2, p4 = t & 3;
  const float* yb = ybuf + (size_t)s * 4096;
  const int c0 = g * 64 + p4 * 16;
  float m = 3.4e38f;
#pragma unroll
  for (int e = 0; e < 16; ++e) m = fminf(m, yb[c0 + e] + bias[c0 + e]);
  m = fminf(m, __shfl_xor(m, 1, 64));
  m = fminf(m, __shfl_xor(m, 2, 64));
  if (p4 == 0) gm[g] = m;
  __syncthreads();
  if (t < 64) {
    float v = gm[t];
    v = fmaxf(v, __shfl_xor(v, 1, 64));
    v = fmaxf(v, __shfl_xor(v, 2, 64));
    v = fmaxf(v, __shfl_xor(v, 4, 64));
    v = fmaxf(v, __shfl_xor(v, 8, 64));
    v = fmaxf(v, __shfl_xor(v, 16, 64));
    v = fmaxf(v, __shfl_xor(v, 32, 64));
    if (t == 0) {
      const int row = undec[s];
      const float sg = 1.0f / (1.0f + expf(-v));
      out[row] = (rand_u[row] < sg) ? 1.0f : 0.0f;
    }
  }
}

extern "C" void kernel_launch(void* const* d_in, const int* in_sizes, int n_in,
                              void* d_out, int out_size, void* d_ws, size_t ws_size,
                              hipStream_t stream) {
  float* x = (float*)d_in[0];           // [8192, 2048] fp32 (mutated in place)
  float* weight = (float*)d_in[1];      // [4096, 2048] fp32 (mutated in place)
  const float* bias = (const float*)d_in[2];
  const float* rand_u = (const float*)d_in[3];
  const int* montn = (const int*)d_in[4];
  float* out = (float*)d_out;

  char* ws = (char*)d_ws;
  int* count = (int*)ws;                         // 4 B
  int* undec = (int*)(ws + 256);                 // 32 KB
  float* ybuf = (float*)(ws + 65536);            // 96*4096*4 = 1.5 MB
  float* gmins = (float*)(ws + 65536 + 1572864); // 2 MB

  convert_split<<<3072, 256, 0, stream>>>(x, weight, montn, count);
  gemm_minmax<<<2048, 256, 0, stream>>>(
      (const unsigned short*)x, (const unsigned short*)weight, bias, gmins);
  finalize_margin<<<2048, 256, 0, stream>>>(gmins, rand_u, out, count, undec,
                                            (float4*)ybuf);
  recompute_rows<<<dim3(64, 16), 256, 0, stream>>>(
      (const unsigned short*)x, (const unsigned short*)weight, count, undec, ybuf);
  decide<<<MAX_UNDEC, 256, 0, stream>>>(ybuf, undec, count, bias, rand_u, out);
}

// Round 6
// 321.928 us; speedup vs baseline: 1.0190x; 1.0190x over previous
//
#include <hip/hip_runtime.h>
#include <cmath>

// ---------------------------------------------------------------------------
// min_max_net: w' = weight with montn columns squared; y = x @ w'^T + bias;
// out[b] = (rand_u[b] < sigmoid(max_g min_{j in g} y[b, g*64+j])) ? 1 : 0
//
// R6: GEMM = 128x128 block, 16x16x32 f16 frags (verified zero-conflict XOR
// swizzle), BK=32 DOUBLE-BUFFERED with distance-1 async prefetch (one
// barrier/iter; DMA overlaps compute), 32KB LDS, launch_bounds(256,4).
// XCD n-slice swizzle. Non-GEMM pipeline = R5 (unchanged).
// fp16 hi*hi GEMM (sigma ~3.6e-4), margin 4e-3, exact recompute of ~16 rows.
// ---------------------------------------------------------------------------

typedef _Float16 f16x8 __attribute__((ext_vector_type(8)));
typedef float f32x4 __attribute__((ext_vector_type(4)));

#define MARGIN_EPS 4e-3f
#define MAX_UNDEC 96

__device__ __forceinline__ void async_load16(const void* gptr, void* lptr) {
  __builtin_amdgcn_global_load_lds(
      (const __attribute__((address_space(1))) void*)gptr,
      (__attribute__((address_space(3))) void*)lptr, 16, 0, 0);
}

__device__ __forceinline__ float us2f(unsigned short u) {
  return (float)__builtin_bit_cast(_Float16, u);
}

// ---- kernel 1: in-place fp32 row -> [hi fp16 | lo fp16], 1 wave per row ----
__global__ void convert_split(float* __restrict__ x, float* __restrict__ wgt,
                              const int* __restrict__ montn,
                              int* __restrict__ count) {
  __shared__ unsigned msk[64];
  const int t = threadIdx.x, l = t & 63, w = t >> 6;
  const int r = blockIdx.x * 4 + w;
  const int use_mask = (r >= 8192) ? 1 : 0;   // block-uniform (4-row blocks)
  if (blockIdx.x == 0 && t == 0) *count = 0;
  if (use_mask) {
    if (t < 64) msk[t] = 0u;
    __syncthreads();
    for (int j = t; j < 512; j += 256) {
      const int c = montn[j];
      atomicOr(&msk[c >> 5], 1u << (c & 31));
    }
    __syncthreads();
  }
  float* rowp = use_mask ? (wgt + (size_t)(r - 8192) * 2048)
                         : (x + (size_t)r * 2048);
  float4 v[8];
#pragma unroll
  for (int j = 0; j < 8; ++j) v[j] = ((const float4*)rowp)[l + 64 * j];
  unsigned mw[8];
#pragma unroll
  for (int j = 0; j < 8; ++j)
    mw[j] = use_mask ? msk[(l >> 3) + 8 * j] : 0u;

  unsigned short* up = (unsigned short*)rowp;
#pragma unroll
  for (int j = 0; j < 8; ++j) {
    unsigned short hs[4], ls[4];
    const float* fv = (const float*)&v[j];
#pragma unroll
    for (int c = 0; c < 4; ++c) {
      float f = fv[c];
      if ((mw[j] >> (4 * (l & 7) + c)) & 1u) f = f * f;
      _Float16 h = (_Float16)f;          // RTNE
      float res = f - (float)h;          // exact in fp32
      _Float16 lo = (_Float16)res;
      hs[c] = __builtin_bit_cast(unsigned short, h);
      ls[c] = __builtin_bit_cast(unsigned short, lo);
    }
    uint2 H, L;
    H.x = (unsigned)hs[0] | ((unsigned)hs[1] << 16);
    H.y = (unsigned)hs[2] | ((unsigned)hs[3] << 16);
    L.x = (unsigned)ls[0] | ((unsigned)ls[1] << 16);
    L.y = (unsigned)ls[2] | ((unsigned)ls[3] << 16);
    *((uint2*)(up + 4 * l + 256 * j)) = H;           // hi plane [0,2048)
    *((uint2*)(up + 2048 + 4 * l + 256 * j)) = L;    // lo plane [2048,4096)
  }
}

// ---- kernel 2: hi*hi GEMM + fused bias/group-min ---------------------------
// Block 128x128, BK=32, dbuf prefetch. 4 waves (2x2), wave 64x64 via 4x4
// MFMA 16x16x32 f16 (16 MFMA/iter/wave). LDS rows 64B; stored 16B chunk
// p at row r holds global chunk p^(r&3) -> conflict-free b128 reads.
__global__ __launch_bounds__(256, 4) void gemm_minmax(
    const unsigned short* __restrict__ X, const unsigned short* __restrict__ W,
    const float* __restrict__ bias, float* __restrict__ gmins) {
  __shared__ unsigned short As[2 * 128 * 32];   // 16 KB (2 buffers)
  __shared__ unsigned short Bs[2 * 128 * 32];   // 16 KB
  const int t = threadIdx.x;
  const int lane = t & 63;
  const int w = t >> 6;
  const int wm = w >> 1, wn = w & 1;
  // XCD swizzle: grid 2048 = 64 m x 32 n; XCD (lin&7) owns a 4-wide n-slice.
  const int lin = blockIdx.x;
  const int sid = lin >> 3;
  const int m0 = (sid >> 2) * 128;
  const int n0 = ((lin & 7) * 4 + (sid & 3)) * 128;

  // staging: per iter, matrix = 128 rows x 32 ushorts (8 KB) in 2 rounds of
  // 4KB. Round c: wave w rows [c*64 + w*16, +16); lane l -> row +(l>>2),
  // stored pos l&3 which holds global chunk (l&3)^((l>>2)&3) (lane-const).
  const int rowS = w * 16 + (lane >> 2);
  const int gch = (((lane & 3) ^ ((lane >> 2) & 3)) * 8);  // ushort offset
  size_t sA[2], sB[2];
#pragma unroll
  for (int c = 0; c < 2; ++c) {
    sA[c] = (size_t)(m0 + c * 64 + rowS) * 4096 + gch;
    sB[c] = (size_t)(n0 + c * 64 + rowS) * 4096 + gch;
  }

  const int am = lane & 15, quad = lane >> 4;
  int aoff[4], boff[4];
#pragma unroll
  for (int i = 0; i < 4; ++i) {
    const int ar = wm * 64 + i * 16 + am;      // ar&3 == am&3
    const int br = wn * 64 + i * 16 + am;
    aoff[i] = ar * 32 + ((quad ^ (am & 3)) * 8);
    boff[i] = br * 32 + ((quad ^ (am & 3)) * 8);
  }

  f32x4 acc[4][4];
#pragma unroll
  for (int i = 0; i < 4; ++i)
#pragma unroll
    for (int j = 0; j < 4; ++j) acc[i][j] = (f32x4){0.f, 0.f, 0.f, 0.f};

  // prologue: stage tile 0 into buffer 0
#pragma unroll
  for (int c = 0; c < 2; ++c) {
    async_load16(X + sA[c], As + c * 2048 + w * 512);
    async_load16(W + sB[c], Bs + c * 2048 + w * 512);
  }

#pragma unroll 1
  for (int it = 0; it < 64; ++it) {
    const int buf = it & 1;
    __syncthreads();  // drains vmcnt: buf's DMAs done; prev compute done
    if (it + 1 < 64) {
      const int kin = (it + 1) * 32;
      const int ob = (buf ^ 1) * 4096;
#pragma unroll
      for (int c = 0; c < 2; ++c) {
        async_load16(X + sA[c] + kin, As + ob + c * 2048 + w * 512);
        async_load16(W + sB[c] + kin, Bs + ob + c * 2048 + w * 512);
      }
    }
    const unsigned short* Ab = As + buf * 4096;
    const unsigned short* Bb = Bs + buf * 4096;
    f16x8 av[4], bv[4];
#pragma unroll
    for (int i = 0; i < 4; ++i) av[i] = *(const f16x8*)(Ab + aoff[i]);
#pragma unroll
    for (int i = 0; i < 4; ++i) bv[i] = *(const f16x8*)(Bb + boff[i]);
#pragma unroll
    for (int mb = 0; mb < 4; ++mb)
#pragma unroll
      for (int nb = 0; nb < 4; ++nb)
        acc[mb][nb] = __builtin_amdgcn_mfma_f32_16x16x32_f16(
            av[mb], bv[nb], acc[mb][nb], 0, 0, 0);
  }

  // epilogue: bias + min over wave's 64 cols (one group) per row
  float bv4[4];
#pragma unroll
  for (int nb = 0; nb < 4; ++nb) bv4[nb] = bias[n0 + wn * 64 + nb * 16 + am];
  const int grp = (n0 >> 6) + wn;
#pragma unroll
  for (int mb = 0; mb < 4; ++mb) {
#pragma unroll
    for (int reg = 0; reg < 4; ++reg) {
      float v = fminf(fminf(acc[mb][0][reg] + bv4[0], acc[mb][1][reg] + bv4[1]),
                      fminf(acc[mb][2][reg] + bv4[2], acc[mb][3][reg] + bv4[3]));
      v = fminf(v, __shfl_xor(v, 1, 64));
      v = fminf(v, __shfl_xor(v, 2, 64));
      v = fminf(v, __shfl_xor(v, 4, 64));
      v = fminf(v, __shfl_xor(v, 8, 64));
      if (am == 0) {
        const int row = m0 + wm * 64 + mb * 16 + quad * 4 + reg;
        gmins[(size_t)row * 64 + grp] = v;
      }
    }
  }
}

// ---- kernel 3: max over groups -> margin test (+ ybuf zeroing) -------------
__global__ void finalize_margin(const float* __restrict__ gmins,
                                const float* __restrict__ rand_u,
                                float* __restrict__ out,
                                int* __restrict__ count, int* __restrict__ undec,
                                float4* __restrict__ ybuf4) {
  if (blockIdx.x < 384)  // zero ybuf: 384*256 float4 = 96*4096 floats
    ybuf4[(size_t)blockIdx.x * 256 + threadIdx.x] = (float4){0.f, 0.f, 0.f, 0.f};
  const int wv = threadIdx.x >> 6, lane = threadIdx.x & 63;
  const int row = blockIdx.x * 4 + wv;
  float v = gmins[(size_t)row * 64 + lane];
  v = fmaxf(v, __shfl_xor(v, 1, 64));
  v = fmaxf(v, __shfl_xor(v, 2, 64));
  v = fmaxf(v, __shfl_xor(v, 4, 64));
  v = fmaxf(v, __shfl_xor(v, 8, 64));
  v = fmaxf(v, __shfl_xor(v, 16, 64));
  v = fmaxf(v, __shfl_xor(v, 32, 64));
  if (lane == 0) {
    const float u = rand_u[row];
    const float slo = 1.0f / (1.0f + expf(-(v - MARGIN_EPS)));
    const float shi = 1.0f / (1.0f + expf(-(v + MARGIN_EPS)));
    if (u < slo) {
      out[row] = 1.0f;
    } else if (u >= shi) {
      out[row] = 0.0f;
    } else {
      const int i = atomicAdd(count, 1);
      if (i < 8192) undec[i] = row;
    }
  }
}

// ---- kernel 4: exact fp32 recompute, W read ONCE ---------------------------
__global__ __launch_bounds__(256) void recompute_rows(
    const unsigned short* __restrict__ X, const unsigned short* __restrict__ W,
    const int* __restrict__ count, const int* __restrict__ undec,
    float* __restrict__ ybuf) {
  __shared__ float wf[64 * 129];   // ~33 KB
  __shared__ float part[256];
  const int g = blockIdx.x, kc = blockIdx.y;
  const int t = threadIdx.x;
  int n = *count;
  if (n > MAX_UNDEC) n = MAX_UNDEC;
  if (n == 0) return;

  {  // stage: thread t -> col t>>2, k-segment t&3 (32 k each)
    const int cl = t >> 2, ks = t & 3;
    const unsigned short* wp =
        W + (size_t)(g * 64 + cl) * 4096 + kc * 128 + ks * 32;
    float* dst = wf + cl * 129 + ks * 32;
#pragma unroll
    for (int i = 0; i < 32; i += 8) {
      uint4 hv = *(const uint4*)(wp + i);
      uint4 lv = *(const uint4*)(wp + 2048 + i);
      const unsigned* hw = (const unsigned*)&hv;
      const unsigned* lw = (const unsigned*)&lv;
#pragma unroll
      for (int m = 0; m < 4; ++m) {
        dst[i + 2 * m] = us2f((unsigned short)(hw[m] & 0xFFFF)) +
                         us2f((unsigned short)(lw[m] & 0xFFFF));
        dst[i + 2 * m + 1] = us2f((unsigned short)(hw[m] >> 16)) +
                             us2f((unsigned short)(lw[m] >> 16));
      }
    }
  }
  __syncthreads();

  const int col = t & 63, kq = t >> 6;   // 32 k per quarter
  const float* wcol = wf + col * 129 + kq * 32;
  for (int s = 0; s < n; ++s) {
    const int row = undec[s];
    const unsigned short* xp = X + (size_t)row * 4096 + kc * 128 + kq * 32;
    float acc = 0.f;
#pragma unroll
    for (int i = 0; i < 32; i += 8) {
      uint4 hv = *(const uint4*)(xp + i);
      uint4 lv = *(const uint4*)(xp + 2048 + i);
      const unsigned* hw = (const unsigned*)&hv;
      const unsigned* lw = (const unsigned*)&lv;
#pragma unroll
      for (int m = 0; m < 4; ++m) {
        const float x0 = us2f((unsigned short)(hw[m] & 0xFFFF)) +
                         us2f((unsigned short)(lw[m] & 0xFFFF));
        const float x1 = us2f((unsigned short)(hw[m] >> 16)) +
                         us2f((unsigned short)(lw[m] >> 16));
        acc = fmaf(x0, wcol[i + 2 * m], acc);
        acc = fmaf(x1, wcol[i + 2 * m + 1], acc);
      }
    }
    part[t] = acc;
    __syncthreads();
    if (t < 64) {
      const float y = part[t] + part[t + 64] + part[t + 128] + part[t + 192];
      atomicAdd(ybuf + (size_t)s * 4096 + g * 64 + t, y);
    }
    __syncthreads();
  }
}

// ---- kernel 5: final decision for undecided rows ---------------------------
__global__ void decide(const float* __restrict__ ybuf,
                       const int* __restrict__ undec, const int* __restrict__ count,
                       const float* __restrict__ bias,
                       const float* __restrict__ rand_u, float* __restrict__ out) {
  __shared__ float gm[64];
  int n = *count;
  if (n > MAX_UNDEC) n = MAX_UNDEC;
  const int s = blockIdx.x;
  if (s >= n) return;
  const int t = threadIdx.x;
  const int g = t >> 2, p4 = t & 3;
  const float* yb = ybuf + (size_t)s * 4096;
  const int c0 = g * 64 + p4 * 16;
  float m = 3.4e38f;
#pragma unroll
  for (int e = 0; e < 16; ++e) m = fminf(m, yb[c0 + e] + bias[c0 + e]);
  m = fminf(m, __shfl_xor(m, 1, 64));
  m = fminf(m, __shfl_xor(m, 2, 64));
  if (p4 == 0) gm[g] = m;
  __syncthreads();
  if (t < 64) {
    float v = gm[t];
    v = fmaxf(v, __shfl_xor(v, 1, 64));
    v = fmaxf(v, __shfl_xor(v, 2, 64));
    v = fmaxf(v, __shfl_xor(v, 4, 64));
    v = fmaxf(v, __shfl_xor(v, 8, 64));
    v = fmaxf(v, __shfl_xor(v, 16, 64));
    v = fmaxf(v, __shfl_xor(v, 32, 64));
    if (t == 0) {
      const int row = undec[s];
      const float sg = 1.0f / (1.0f + expf(-v));
      out[row] = (rand_u[row] < sg) ? 1.0f : 0.0f;
    }
  }
}

extern "C" void kernel_launch(void* const* d_in, const int* in_sizes, int n_in,
                              void* d_out, int out_size, void* d_ws, size_t ws_size,
                              hipStream_t stream) {
  float* x = (float*)d_in[0];           // [8192, 2048] fp32 (mutated in place)
  float* weight = (float*)d_in[1];      // [4096, 2048] fp32 (mutated in place)
  const float* bias = (const float*)d_in[2];
  const float* rand_u = (const float*)d_in[3];
  const int* montn = (const int*)d_in[4];
  float* out = (float*)d_out;

  char* ws = (char*)d_ws;
  int* count = (int*)ws;                         // 4 B
  int* undec = (int*)(ws + 256);                 // 32 KB
  float* ybuf = (float*)(ws + 65536);            // 96*4096*4 = 1.5 MB
  float* gmins = (float*)(ws + 65536 + 1572864); // 2 MB

  convert_split<<<3072, 256, 0, stream>>>(x, weight, montn, count);
  gemm_minmax<<<2048, 256, 0, stream>>>(
      (const unsigned short*)x, (const unsigned short*)weight, bias, gmins);
  finalize_margin<<<2048, 256, 0, stream>>>(gmins, rand_u, out, count, undec,
                                            (float4*)ybuf);
  recompute_rows<<<dim3(64, 16), 256, 0, stream>>>(
      (const unsigned short*)x, (const unsigned short*)weight, count, undec, ybuf);
  decide<<<MAX_UNDEC, 256, 0, stream>>>(ybuf, undec, count, bias, rand_u, out);
}

// Round 7
// 290.963 us; speedup vs baseline: 1.1274x; 1.1064x over previous
//
#include <hip/hip_runtime.h>
#include <cmath>

// ---------------------------------------------------------------------------
// min_max_net: w' = weight with montn columns squared; y = x @ w'^T + bias;
// out[b] = (rand_u[b] < sigmoid(max_g min_{j in g} y[b, g*64+j])) ? 1 : 0
//
// R7: GEMM = R3's verified body (BK=64, 128B LDS rows, 3-bit XOR swizzle,
// zero conflicts, 2-barrier K-loop) with __launch_bounds__(256,4) to allow
// 4 blocks/CU (R3 sat at 3 due to (256,2)), + XCD n-slice block swizzle.
// Non-GEMM = R5/R6 pipeline (in-register convert, fused margin, 1-pass
// recompute). fp16 hi*hi GEMM (sigma ~3.6e-4), margin 4e-3, exact fp32
// recompute of undecided rows (~16 expected, cap 96).
// ---------------------------------------------------------------------------

typedef _Float16 f16x8 __attribute__((ext_vector_type(8)));
typedef float f32x4 __attribute__((ext_vector_type(4)));

#define MARGIN_EPS 4e-3f
#define MAX_UNDEC 96

__device__ __forceinline__ void async_load16(const void* gptr, void* lptr) {
  __builtin_amdgcn_global_load_lds(
      (const __attribute__((address_space(1))) void*)gptr,
      (__attribute__((address_space(3))) void*)lptr, 16, 0, 0);
}

__device__ __forceinline__ float us2f(unsigned short u) {
  return (float)__builtin_bit_cast(_Float16, u);
}

// ---- kernel 1: in-place fp32 row -> [hi fp16 | lo fp16], 1 wave per row ----
__global__ void convert_split(float* __restrict__ x, float* __restrict__ wgt,
                              const int* __restrict__ montn,
                              int* __restrict__ count) {
  __shared__ unsigned msk[64];
  const int t = threadIdx.x, l = t & 63, w = t >> 6;
  const int r = blockIdx.x * 4 + w;
  const int use_mask = (r >= 8192) ? 1 : 0;   // block-uniform (4-row blocks)
  if (blockIdx.x == 0 && t == 0) *count = 0;
  if (use_mask) {
    if (t < 64) msk[t] = 0u;
    __syncthreads();
    for (int j = t; j < 512; j += 256) {
      const int c = montn[j];
      atomicOr(&msk[c >> 5], 1u << (c & 31));
    }
    __syncthreads();
  }
  float* rowp = use_mask ? (wgt + (size_t)(r - 8192) * 2048)
                         : (x + (size_t)r * 2048);
  float4 v[8];
#pragma unroll
  for (int j = 0; j < 8; ++j) v[j] = ((const float4*)rowp)[l + 64 * j];
  unsigned mw[8];
#pragma unroll
  for (int j = 0; j < 8; ++j)
    mw[j] = use_mask ? msk[(l >> 3) + 8 * j] : 0u;

  unsigned short* up = (unsigned short*)rowp;
#pragma unroll
  for (int j = 0; j < 8; ++j) {
    unsigned short hs[4], ls[4];
    const float* fv = (const float*)&v[j];
#pragma unroll
    for (int c = 0; c < 4; ++c) {
      float f = fv[c];
      if ((mw[j] >> (4 * (l & 7) + c)) & 1u) f = f * f;
      _Float16 h = (_Float16)f;          // RTNE
      float res = f - (float)h;          // exact in fp32
      _Float16 lo = (_Float16)res;
      hs[c] = __builtin_bit_cast(unsigned short, h);
      ls[c] = __builtin_bit_cast(unsigned short, lo);
    }
    uint2 H, L;
    H.x = (unsigned)hs[0] | ((unsigned)hs[1] << 16);
    H.y = (unsigned)hs[2] | ((unsigned)hs[3] << 16);
    L.x = (unsigned)ls[0] | ((unsigned)ls[1] << 16);
    L.y = (unsigned)ls[2] | ((unsigned)ls[3] << 16);
    *((uint2*)(up + 4 * l + 256 * j)) = H;           // hi plane [0,2048)
    *((uint2*)(up + 2048 + 4 * l + 256 * j)) = L;    // lo plane [2048,4096)
  }
}

// ---- kernel 2: hi*hi GEMM + fused bias/group-min ---------------------------
// R3's verified body: K=2048 over 32 iters of BK=64. Block 128x128, 4 waves
// (2x2), wave 64x64 via 4x4 MFMA 16x16x32 f16. 128B LDS rows, 16B chunk c
// stored at c^(row&7) -> zero bank conflicts (measured R2/R3/R4).
// launch_bounds(256,4): VGPR<=128 & LDS 32KB allow 4 blocks/CU.
__global__ __launch_bounds__(256, 4) void gemm_minmax(
    const unsigned short* __restrict__ X, const unsigned short* __restrict__ W,
    const float* __restrict__ bias, float* __restrict__ gmins) {
  __shared__ unsigned short As[128 * 64];   // 16 KB
  __shared__ unsigned short Bs[128 * 64];   // 16 KB
  const int t = threadIdx.x;
  const int lane = t & 63;
  const int w = t >> 6;
  const int wm = w >> 1, wn = w & 1;
  // XCD swizzle: grid 2048 = 64 m x 32 n; XCD (lin&7) owns a 4-wide n-slice.
  const int lin = blockIdx.x;
  const int sid = lin >> 3;
  const int m0 = (sid >> 2) * 128;
  const int n0 = ((lin & 7) * 4 + (sid & 3)) * 128;

  const int rowBase = w * 8 + (lane >> 3);
  const int gchunk = ((lane & 7) ^ ((lane >> 3) & 7)) * 8;  // ushort offset
  size_t sA[4], sB[4];
#pragma unroll
  for (int c = 0; c < 4; ++c) {
    sA[c] = (size_t)(m0 + c * 32 + rowBase) * 4096 + gchunk;
    sB[c] = (size_t)(n0 + c * 32 + rowBase) * 4096 + gchunk;
  }
  unsigned short* ldsA[4];
  unsigned short* ldsB[4];
#pragma unroll
  for (int c = 0; c < 4; ++c) {
    ldsA[c] = As + c * 2048 + w * 512;  // wave-uniform bases (ushort units)
    ldsB[c] = Bs + c * 2048 + w * 512;
  }

  const int am = lane & 15, quad = lane >> 4;
  int arow[4], brow[4];
#pragma unroll
  for (int i = 0; i < 4; ++i) {
    arow[i] = (wm * 64 + i * 16 + am) * 64;
    brow[i] = (wn * 64 + i * 16 + am) * 64;
  }
  int swz[2];
#pragma unroll
  for (int h = 0; h < 2; ++h) swz[h] = (((h << 2) + quad) ^ (am & 7)) * 8;

  f32x4 acc[4][4];
#pragma unroll
  for (int i = 0; i < 4; ++i)
#pragma unroll
    for (int j = 0; j < 4; ++j) acc[i][j] = (f32x4){0.f, 0.f, 0.f, 0.f};

#pragma unroll 1
  for (int it = 0; it < 32; ++it) {
    const int kin = it * 64;
    __syncthreads();  // previous iteration's LDS reads complete
#pragma unroll
    for (int c = 0; c < 4; ++c) {
      async_load16(X + sA[c] + kin, ldsA[c]);
      async_load16(W + sB[c] + kin, ldsB[c]);
    }
    __syncthreads();  // staging complete (drains vmcnt)

#pragma unroll
    for (int h = 0; h < 2; ++h) {
      f16x8 av[4], bv[4];
#pragma unroll
      for (int i = 0; i < 4; ++i) av[i] = *(const f16x8*)(As + arow[i] + swz[h]);
#pragma unroll
      for (int i = 0; i < 4; ++i) bv[i] = *(const f16x8*)(Bs + brow[i] + swz[h]);
#pragma unroll
      for (int mb = 0; mb < 4; ++mb)
#pragma unroll
        for (int nb = 0; nb < 4; ++nb)
          acc[mb][nb] = __builtin_amdgcn_mfma_f32_16x16x32_f16(
              av[mb], bv[nb], acc[mb][nb], 0, 0, 0);
    }
  }

  float bv4[4];
#pragma unroll
  for (int nb = 0; nb < 4; ++nb) bv4[nb] = bias[n0 + wn * 64 + nb * 16 + am];
  const int grp = (n0 >> 6) + wn;
#pragma unroll
  for (int mb = 0; mb < 4; ++mb) {
#pragma unroll
    for (int reg = 0; reg < 4; ++reg) {
      float v = fminf(fminf(acc[mb][0][reg] + bv4[0], acc[mb][1][reg] + bv4[1]),
                      fminf(acc[mb][2][reg] + bv4[2], acc[mb][3][reg] + bv4[3]));
      v = fminf(v, __shfl_xor(v, 1, 64));
      v = fminf(v, __shfl_xor(v, 2, 64));
      v = fminf(v, __shfl_xor(v, 4, 64));
      v = fminf(v, __shfl_xor(v, 8, 64));
      if (am == 0) {
        const int row = m0 + wm * 64 + mb * 16 + quad * 4 + reg;
        gmins[(size_t)row * 64 + grp] = v;
      }
    }
  }
}

// ---- kernel 3: max over groups -> margin test (+ ybuf zeroing) -------------
__global__ void finalize_margin(const float* __restrict__ gmins,
                                const float* __restrict__ rand_u,
                                float* __restrict__ out,
                                int* __restrict__ count, int* __restrict__ undec,
                                float4* __restrict__ ybuf4) {
  if (blockIdx.x < 384)  // zero ybuf: 384*256 float4 = 96*4096 floats
    ybuf4[(size_t)blockIdx.x * 256 + threadIdx.x] = (float4){0.f, 0.f, 0.f, 0.f};
  const int wv = threadIdx.x >> 6, lane = threadIdx.x & 63;
  const int row = blockIdx.x * 4 + wv;
  float v = gmins[(size_t)row * 64 + lane];
  v = fmaxf(v, __shfl_xor(v, 1, 64));
  v = fmaxf(v, __shfl_xor(v, 2, 64));
  v = fmaxf(v, __shfl_xor(v, 4, 64));
  v = fmaxf(v, __shfl_xor(v, 8, 64));
  v = fmaxf(v, __shfl_xor(v, 16, 64));
  v = fmaxf(v, __shfl_xor(v, 32, 64));
  if (lane == 0) {
    const float u = rand_u[row];
    const float slo = 1.0f / (1.0f + expf(-(v - MARGIN_EPS)));
    const float shi = 1.0f / (1.0f + expf(-(v + MARGIN_EPS)));
    if (u < slo) {
      out[row] = 1.0f;
    } else if (u >= shi) {
      out[row] = 0.0f;
    } else {
      const int i = atomicAdd(count, 1);
      if (i < 8192) undec[i] = row;
    }
  }
}

// ---- kernel 4: exact fp32 recompute, W read ONCE ---------------------------
__global__ __launch_bounds__(256) void recompute_rows(
    const unsigned short* __restrict__ X, const unsigned short* __restrict__ W,
    const int* __restrict__ count, const int* __restrict__ undec,
    float* __restrict__ ybuf) {
  __shared__ float wf[64 * 129];   // ~33 KB
  __shared__ float part[256];
  const int g = blockIdx.x, kc = blockIdx.y;
  const int t = threadIdx.x;
  int n = *count;
  if (n > MAX_UNDEC) n = MAX_UNDEC;
  if (n == 0) return;

  {  // stage: thread t -> col t>>2, k-segment t&3 (32 k each)
    const int cl = t >> 2, ks = t & 3;
    const unsigned short* wp =
        W + (size_t)(g * 64 + cl) * 4096 + kc * 128 + ks * 32;
    float* dst = wf + cl * 129 + ks * 32;
#pragma unroll
    for (int i = 0; i < 32; i += 8) {
      uint4 hv = *(const uint4*)(wp + i);
      uint4 lv = *(const uint4*)(wp + 2048 + i);
      const unsigned* hw = (const unsigned*)&hv;
      const unsigned* lw = (const unsigned*)&lv;
#pragma unroll
      for (int m = 0; m < 4; ++m) {
        dst[i + 2 * m] = us2f((unsigned short)(hw[m] & 0xFFFF)) +
                         us2f((unsigned short)(lw[m] & 0xFFFF));
        dst[i + 2 * m + 1] = us2f((unsigned short)(hw[m] >> 16)) +
                             us2f((unsigned short)(lw[m] >> 16));
      }
    }
  }
  __syncthreads();

  const int col = t & 63, kq = t >> 6;   // 32 k per quarter
  const float* wcol = wf + col * 129 + kq * 32;
  for (int s = 0; s < n; ++s) {
    const int row = undec[s];
    const unsigned short* xp = X + (size_t)row * 4096 + kc * 128 + kq * 32;
    float acc = 0.f;
#pragma unroll
    for (int i = 0; i < 32; i += 8) {
      uint4 hv = *(const uint4*)(xp + i);
      uint4 lv = *(const uint4*)(xp + 2048 + i);
      const unsigned* hw = (const unsigned*)&hv;
      const unsigned* lw = (const unsigned*)&lv;
#pragma unroll
      for (int m = 0; m < 4; ++m) {
        const float x0 = us2f((unsigned short)(hw[m] & 0xFFFF)) +
                         us2f((unsigned short)(lw[m] & 0xFFFF));
        const float x1 = us2f((unsigned short)(hw[m] >> 16)) +
                         us2f((unsigned short)(lw[m] >> 16));
        acc = fmaf(x0, wcol[i + 2 * m], acc);
        acc = fmaf(x1, wcol[i + 2 * m + 1], acc);
      }
    }
    part[t] = acc;
    __syncthreads();
    if (t < 64) {
      const float y = part[t] + part[t + 64] + part[t + 128] + part[t + 192];
      atomicAdd(ybuf + (size_t)s * 4096 + g * 64 + t, y);
    }
    __syncthreads();
  }
}

// ---- kernel 5: final decision for undecided rows ---------------------------
__global__ void decide(const float* __restrict__ ybuf,
                       const int* __restrict__ undec, const int* __restrict__ count,
                       const float* __restrict__ bias,
                       const float* __restrict__ rand_u, float* __restrict__ out) {
  __shared__ float gm[64];
  int n = *count;
  if (n > MAX_UNDEC) n = MAX_UNDEC;
  const int s = blockIdx.x;
  if (s >= n) return;
  const int t = threadIdx.x;
  const int g = t >> 2, p4 = t & 3;
  const float* yb = ybuf + (size_t)s * 4096;
  const int c0 = g * 64 + p4 * 16;
  float m = 3.4e38f;
#pragma unroll
  for (int e = 0; e < 16; ++e) m = fminf(m, yb[c0 + e] + bias[c0 + e]);
  m = fminf(m, __shfl_xor(m, 1, 64));
  m = fminf(m, __shfl_xor(m, 2, 64));
  if (p4 == 0) gm[g] = m;
  __syncthreads();
  if (t < 64) {
    float v = gm[t];
    v = fmaxf(v, __shfl_xor(v, 1, 64));
    v = fmaxf(v, __shfl_xor(v, 2, 64));
    v = fmaxf(v, __shfl_xor(v, 4, 64));
    v = fmaxf(v, __shfl_xor(v, 8, 64));
    v = fmaxf(v, __shfl_xor(v, 16, 64));
    v = fmaxf(v, __shfl_xor(v, 32, 64));
    if (t == 0) {
      const int row = undec[s];
      const float sg = 1.0f / (1.0f + expf(-v));
      out[row] = (rand_u[row] < sg) ? 1.0f : 0.0f;
    }
  }
}

extern "C" void kernel_launch(void* const* d_in, const int* in_sizes, int n_in,
                              void* d_out, int out_size, void* d_ws, size_t ws_size,
                              hipStream_t stream) {
  float* x = (float*)d_in[0];           // [8192, 2048] fp32 (mutated in place)
  float* weight = (float*)d_in[1];      // [4096, 2048] fp32 (mutated in place)
  const float* bias = (const float*)d_in[2];
  const float* rand_u = (const float*)d_in[3];
  const int* montn = (const int*)d_in[4];
  float* out = (float*)d_out;

  char* ws = (char*)d_ws;
  int* count = (int*)ws;                         // 4 B
  int* undec = (int*)(ws + 256);                 // 32 KB
  float* ybuf = (float*)(ws + 65536);            // 96*4096*4 = 1.5 MB
  float* gmins = (float*)(ws + 65536 + 1572864); // 2 MB

  convert_split<<<3072, 256, 0, stream>>>(x, weight, montn, count);
  gemm_minmax<<<2048, 256, 0, stream>>>(
      (const unsigned short*)x, (const unsigned short*)weight, bias, gmins);
  finalize_margin<<<2048, 256, 0, stream>>>(gmins, rand_u, out, count, undec,
                                            (float4*)ybuf);
  recompute_rows<<<dim3(64, 16), 256, 0, stream>>>(
      (const unsigned short*)x, (const unsigned short*)weight, count, undec, ybuf);
  decide<<<MAX_UNDEC, 256, 0, stream>>>(ybuf, undec, count, bias, rand_u, out);
}